// Round 8
// baseline (46.290 us; speedup 1.0000x reference)
//
#include <hip/hip_runtime.h>
#include <math.h>

#define B 8
#define S 4096
#define H 1024
#define NSEG 64
#define NPARA 32
#define NA 8
#define BS (B * S)
#define ROWS_PER_BLK 32
#define BLKS_PER_B (S / ROWS_PER_BLK)   // 128
#define NBLK (B * BLKS_PER_B)           // 1024

// async global->LDS, 16B per lane; LDS dest is wave-uniform base (+lane*16 HW)
__device__ __forceinline__ void gload_lds16(const float4* g, float4* l)
{
    __builtin_amdgcn_global_load_lds(
        (const __attribute__((address_space(1))) void*)g,
        (__attribute__((address_space(3))) void*)l, 16, 0, 0);
}

// online-LSE merge: x = running max, y = running scaled sum
__device__ __forceinline__ float2 lse_merge(float2 A, float2 Bv)
{
    float m = fmaxf(A.x, Bv.x);
    float s = 0.f;
    if (A.y > 0.f)  s += A.y * expf(A.x - m);
    if (Bv.y > 0.f) s += Bv.y * expf(Bv.x - m);
    return make_float2(m, s);
}

// ---------------------------------------------------------------------------
// Kernel 1: latency-saturated streaming dots. 1024 blocks x 32 rows.
// Each wave: 8 rows via a PRIVATE 3-buffer LDS ring filled by
// global_load_lds, counted vmcnt(8) (2 rows in flight), NO barriers in the
// stream loop. Packed butterfly reduce; fused masked-LSE + segment partials.
// ---------------------------------------------------------------------------
__global__ __launch_bounds__(256, 3) void dots_kernel(
    const float4* __restrict__ seq4,
    const float4* __restrict__ Wqa4,     // (H*2/4)
    const float4* __restrict__ Wsp4,     // (H/4)
    const float4* __restrict__ Wrank4,   // (H/4)
    const int*    __restrict__ tt,
    const int*    __restrict__ sent_starts,
    float4* __restrict__ sc4,            // (B*S) {d0,d1,d_sp,d_rank}
    float4* __restrict__ lse_part,       // (NBLK) {m0,s0,m1,s1}
    float4* __restrict__ segpart,        // (NBLK) {jlo(int),sumA,sumB,0}
    float*  __restrict__ out)
{
    const int blk   = blockIdx.x;
    const int b     = blk >> 7;                  // / BLKS_PER_B
    const int rbase = (blk & 127) * ROWS_PER_BLK;
    const int t     = threadIdx.x;
    const int w     = t >> 6, lane = t & 63;

    if (blk == 0 && t == 0) { out[0] = 0.f; out[1] = 0.f; out[2] = 0.f; }

    __shared__ float4 ring[4][3][256];           // 48 KB: wave-private rings
    __shared__ int    ssh[NSEG + 1];
    __shared__ int    rowseg[ROWS_PER_BLK];
    __shared__ int    ttsh[ROWS_PER_BLK];
    __shared__ float4 lsep[4];
    __shared__ float2 wacc[4];
    __shared__ int    jlo_sh;

    // ---- weight preload (float4; lane covers chunk lane+64c) ----------------
    float4 qA[4], qB[4], spv[4], rkv[4];
#pragma unroll
    for (int c = 0; c < 4; ++c) {
        const int ch = lane + 64 * c;
        qA[c]  = Wqa4[ch * 2];       // {W[h][0],W[h][1],W[h+1][0],W[h+1][1]}
        qB[c]  = Wqa4[ch * 2 + 1];   // h+2, h+3
        spv[c] = Wsp4[ch];
        rkv[c] = Wrank4[ch];
    }

    // ---- per-block tables ----------------------------------------------------
    if (t < NSEG + 1) ssh[t] = sent_starts[b * (NSEG + 1) + t];
    __syncthreads();
    if (t < ROWS_PER_BLK) {
        ttsh[t] = tt[b * S + rbase + t];
        const int r = rbase + t;
        int j = -1;
        for (int k = 0; k < NSEG; ++k) {
            int en = ssh[k + 1];
            if (en == -1) break;
            if (r >= ssh[k] && r < en) { j = k; break; }
        }
        rowseg[t] = j;
    }
    __syncthreads();
    if (t == 0) {
        int jl = -1;
        for (int i = 0; i < ROWS_PER_BLK; ++i)
            if (rowseg[i] >= 0) { jl = rowseg[i]; break; }
        jlo_sh = jl;
    }
    __syncthreads();
    const int jlo = jlo_sh;

    // ---- wave-private pipelined stream --------------------------------------
    const float4* base = seq4 + (size_t)(b * S + rbase) * (H / 4);
    float mm = -INFINITY, ssum = 0.f;        // lane0: start-LSE; lane1: end-LSE
    float segA = 0.f, segB = 0.f;            // lane2: d_sp segment partials
    float res[8];

#define STAGE(r, buf)                                                         \
    {                                                                         \
        asm volatile("" ::: "memory");                                        \
        const float4* gs = base + (size_t)(w * 8 + (r)) * 256;                \
        float4* ld = &ring[w][buf][0];                                        \
        gload_lds16(gs +   0 + lane, ld +   0);                               \
        gload_lds16(gs +  64 + lane, ld +  64);                               \
        gload_lds16(gs + 128 + lane, ld + 128);                               \
        gload_lds16(gs + 192 + lane, ld + 192);                               \
    }

#define WAITVM(n) asm volatile("s_waitcnt vmcnt(" #n ")" ::: "memory")

#define FMA_C(c)                                                              \
    {   float4 v = rp[lane + 64 * (c)];                                       \
        a0 += v.x*qA[c].x  + v.y*qA[c].z  + v.z*qB[c].x  + v.w*qB[c].z;       \
        a1 += v.x*qA[c].y  + v.y*qA[c].w  + v.z*qB[c].y  + v.w*qB[c].w;       \
        a2 += v.x*spv[c].x + v.y*spv[c].y + v.z*spv[c].z + v.w*spv[c].w;      \
        a3 += v.x*rkv[c].x + v.y*rkv[c].y + v.z*rkv[c].z + v.w*rkv[c].w; }

#define COMPUTE(r, buf)                                                       \
    {                                                                         \
        const int lrow = w * 8 + (r);                                         \
        const float4* rp = &ring[w][buf][0];                                  \
        float a0 = 0.f, a1 = 0.f, a2 = 0.f, a3 = 0.f;                         \
        FMA_C(0) FMA_C(1) FMA_C(2) FMA_C(3)                                   \
        float u01 = (lane & 1) ? a0 : a1;                                     \
        float x01 = ((lane & 1) ? a1 : a0) + __shfl_xor(u01, 1);              \
        float u23 = (lane & 1) ? a2 : a3;                                     \
        float x23 = ((lane & 1) ? a3 : a2) + __shfl_xor(u23, 1);              \
        float uu  = (lane & 2) ? x01 : x23;                                   \
        float x   = ((lane & 2) ? x23 : x01) + __shfl_xor(uu, 2);             \
        x += __shfl_xor(x, 4); x += __shfl_xor(x, 8);                         \
        x += __shfl_xor(x, 16); x += __shfl_xor(x, 32);                       \
        if (ttsh[lrow] == 1) {                                                \
            float mn = fmaxf(mm, x);                                          \
            ssum = ssum * expf(mm - mn) + expf(x - mn);                       \
            mm = mn;                                                          \
        }                                                                     \
        const int j = rowseg[lrow];                                           \
        if (j >= 0) { if (j == jlo) segA += x; else segB += x; }              \
        res[r] = x;                                                           \
    }

    STAGE(0, 0);
    STAGE(1, 1);
    STAGE(2, 2);
    WAITVM(8);  COMPUTE(0, 0);
    STAGE(3, 0);
    WAITVM(8);  COMPUTE(1, 1);
    STAGE(4, 1);
    WAITVM(8);  COMPUTE(2, 2);
    STAGE(5, 2);
    WAITVM(8);  COMPUTE(3, 0);
    STAGE(6, 0);
    WAITVM(8);  COMPUTE(4, 1);
    STAGE(7, 1);
    WAITVM(8);  COMPUTE(5, 2);
    WAITVM(4);  COMPUTE(6, 0);
    WAITVM(0);  COMPUTE(7, 1);

#undef STAGE
#undef WAITVM
#undef FMA_C
#undef COMPUTE

    // ---- deferred score stores (16B per row from lanes 0..3) -----------------
    if (lane < 4) {
#pragma unroll
        for (int r = 0; r < 8; ++r)
            ((float*)(sc4 + (size_t)b * S + rbase + w * 8 + r))[lane] = res[r];
    }

    {
        float mE = __shfl(mm, 1),   sE = __shfl(ssum, 1);
        float sa = __shfl(segA, 2), sb = __shfl(segB, 2);
        if (lane == 0) {
            lsep[w] = make_float4(mm, ssum, mE, sE);
            wacc[w] = make_float2(sa, sb);
        }
    }
    __syncthreads();
    if (t == 0) {
        float2 L0 = make_float2(lsep[0].x, lsep[0].y);
        float2 L1 = make_float2(lsep[0].z, lsep[0].w);
        float SA = wacc[0].x, SB = wacc[0].y;
#pragma unroll
        for (int i = 1; i < 4; ++i) {
            L0 = lse_merge(L0, make_float2(lsep[i].x, lsep[i].y));
            L1 = lse_merge(L1, make_float2(lsep[i].z, lsep[i].w));
            SA += wacc[i].x; SB += wacc[i].y;
        }
        lse_part[blk] = make_float4(L0.x, L0.y, L1.x, L1.y);
        segpart[blk]  = make_float4(__int_as_float(jlo), SA, SB, 0.f);
    }
}

// ---------------------------------------------------------------------------
// block reduce (sum) for ListMLE
// ---------------------------------------------------------------------------
__device__ __forceinline__ float blk_reduce1(float v, float* wred1, int t)
{
    const int lane = t & 63, w = t >> 6;
#pragma unroll
    for (int off = 32; off > 0; off >>= 1) v += __shfl_xor(v, off);
    if (lane == 0) wred1[w] = v;
    __syncthreads();
    float r = wred1[0] + wred1[1] + wred1[2] + wred1[3];
    __syncthreads();
    return r;
}

__device__ float listmle_block(const float* fs, const float* fl, float* se,
                               int n, float* wred1, int t)
{
    if (t < n) se[t] = (fl[t] != -1.0f) ? expf(fs[t]) : 0.0f;
    __syncthreads();
    float lp = 0.0f;
    if (t < n && fl[t] >= 0.5f) {
        float fj = fl[t];
        float rest = 0.0f;
        for (int k = 0; k < n; ++k)
            if (fl[k] < fj) rest += se[k];
        lp = fs[t] - logf(se[t] + rest);
    }
    float tot = blk_reduce1(lp, wred1, t);
    return -tot;
}

// ---------------------------------------------------------------------------
// Kernel 2: one block per batch. Merge 128 LSE partials, fold 128 segment
// partials (LDS atomics), 2x ListMLE, span loss; atomicAdd into out.
// ---------------------------------------------------------------------------
__global__ __launch_bounds__(256) void batch_kernel(
    const float4* __restrict__ sc4,
    const float4* __restrict__ lse_part,
    const float4* __restrict__ segpart,
    const int*    __restrict__ tt,
    const int*    __restrict__ sent_starts,
    const int*    __restrict__ para_starts,
    const float*  __restrict__ para_labels,
    const float*  __restrict__ sp_labels,
    const int*    __restrict__ starts,
    const int*    __restrict__ ends,
    float* __restrict__ out)
{
    const int b = blockIdx.x;
    const int t = threadIdx.x;
    const int lane = t & 63, w = t >> 6;

    __shared__ float4 lsew[2];
    __shared__ float  segsum[NSEG + 2];
    __shared__ int    ssh[NSEG + 1];
    __shared__ float  wred1[4];
    __shared__ float  fsb[1 + NSEG], flb[1 + NSEG], seb[1 + NSEG];
    __shared__ float  lse_sh[2];

    const float4* sb  = sc4 + (size_t)b * S;
    const int*    ttb = tt + b * S;

    if (t < NSEG + 2) segsum[t] = 0.f;
    if (t < NSEG + 1) ssh[t] = sent_starts[b * (NSEG + 1) + t];
    __syncthreads();

    // ---- merge 128 LSE partials + fold 128 segment partials -----------------
    if (t < BLKS_PER_B) {
        float4 P = lse_part[(size_t)b * BLKS_PER_B + t];
        float2 L0 = make_float2(P.x, P.y);
        float2 L1 = make_float2(P.z, P.w);
#pragma unroll
        for (int off = 32; off > 0; off >>= 1) {
            float2 O0 = make_float2(__shfl_xor(L0.x, off), __shfl_xor(L0.y, off));
            float2 O1 = make_float2(__shfl_xor(L1.x, off), __shfl_xor(L1.y, off));
            L0 = lse_merge(L0, O0);
            L1 = lse_merge(L1, O1);
        }
        if (lane == 0) lsew[w] = make_float4(L0.x, L0.y, L1.x, L1.y);

        float4 SP = segpart[(size_t)b * BLKS_PER_B + t];
        int jl = __float_as_int(SP.x);
        if (jl >= 0) {
            atomicAdd(&segsum[jl], SP.y);
            atomicAdd(&segsum[jl + 1], SP.z);
        }
    }
    __syncthreads();
    if (t == 0) {
        float2 M0 = lse_merge(make_float2(lsew[0].x, lsew[0].y),
                              make_float2(lsew[1].x, lsew[1].y));
        float2 M1 = lse_merge(make_float2(lsew[0].z, lsew[0].w),
                              make_float2(lsew[1].z, lsew[1].w));
        lse_sh[0] = M0.x + logf(M0.y);
        lse_sh[1] = M1.x + logf(M1.y);
    }

    // ---- sp ListMLE ---------------------------------------------------------
    if (t == 0) { fsb[0] = sb[0].z; flb[0] = 0.5f; }       // sent_thres
    if (t < NSEG) {
        int st = ssh[t];
        int en = ssh[t + 1];
        float score;
        if (en != -1) {
            int stc = min(max(st, 0), S);
            int enc = max(min(max(en, 0), S), stc + 1);
            score = segsum[t] / (float)(enc - stc);
        } else {
            score = sb[S - 1].z;                           // d_sp at last row
        }
        fsb[1 + t] = score;
        flb[1 + t] = sp_labels[b * NSEG + t];
    }
    __syncthreads();
    float sp_loss_b = listmle_block(fsb, flb, seb, 1 + NSEG, wred1, t);

    // ---- rank ListMLE -------------------------------------------------------
    if (t == 0) { fsb[0] = sb[0].w; flb[0] = 0.5f; }       // rank_thres
    if (t < NPARA) {
        int ps = para_starts[b * NPARA + t];
        fsb[1 + t] = sb[ps].w;
        flb[1 + t] = para_labels[b * NPARA + t];
    }
    __syncthreads();
    float rank_loss_b = listmle_block(fsb, flb, seb, 1 + NPARA, wred1, t);

    // ---- span loss (parallel over answers) ----------------------------------
    float e_a = 0.f;
    if (t < NA) {
        const float lse0 = lse_sh[0], lse1 = lse_sh[1];
        int tsv = starts[b * NA + t];
        int tev = ends[b * NA + t];
        float lt = 0.f;
        if (tsv != -1) {
            int sf = min(max(tsv, 0), S - 1);
            float sl = (ttb[sf] == 1) ? sb[sf].x : -INFINITY;
            lt += -(sl - lse0);
        }
        if (tev != -1) {
            int sf = min(max(tev, 0), S - 1);
            float el = (ttb[sf] == 1) ? sb[sf].y : -INFINITY;
            lt += -(el - lse1);
        }
        float lp = -lt;
        e_a = (lp == 0.0f) ? 0.f : expf(lp);
    }
#pragma unroll
    for (int off = 4; off > 0; off >>= 1) e_a += __shfl_xor(e_a, off, 8);
    if (t == 0) {
        float logm = (e_a > 0.f) ? logf(e_a) : 0.f;
        atomicAdd(out + 0, rank_loss_b + sp_loss_b - logm);
        atomicAdd(out + 1, rank_loss_b);
        atomicAdd(out + 2, sp_loss_b);
    }
}

extern "C" void kernel_launch(void* const* d_in, const int* in_sizes, int n_in,
                              void* d_out, int out_size, void* d_ws, size_t ws_size,
                              hipStream_t stream)
{
    const float* seq         = (const float*)d_in[0];
    const int*   tt          = (const int*)  d_in[1];
    const int*   sent_starts = (const int*)  d_in[2];
    const int*   para_starts = (const int*)  d_in[3];
    const float* para_labels = (const float*)d_in[4];
    const float* sp_labels   = (const float*)d_in[5];
    const int*   starts      = (const int*)  d_in[6];
    const int*   ends        = (const int*)  d_in[7];
    const float* Wqa         = (const float*)d_in[8];
    const float* Wrank       = (const float*)d_in[10];
    const float* Wsp         = (const float*)d_in[12];

    float*  out      = (float*)d_out;
    float4* sc4      = (float4*)d_ws;            // B*S float4 = 512 KB
    float4* lse_part = sc4 + (size_t)BS;         // NBLK
    float4* segpart  = lse_part + NBLK;          // NBLK

    dots_kernel<<<NBLK, 256, 0, stream>>>((const float4*)seq,
                                          (const float4*)Wqa,
                                          (const float4*)Wsp,
                                          (const float4*)Wrank,
                                          tt, sent_starts,
                                          sc4, lse_part, segpart, out);
    batch_kernel<<<B, 256, 0, stream>>>(sc4, lse_part, segpart, tt, sent_starts,
                                        para_starts, para_labels, sp_labels,
                                        starts, ends, out);
}

// Round 9
// 43.623 us; speedup vs baseline: 1.0612x; 1.0612x over previous
//
#include <hip/hip_runtime.h>
#include <math.h>

#define B 8
#define S 4096
#define H 1024
#define NSEG 64
#define NPARA 32
#define NA 8
#define BS (B * S)
#define ROWS_PER_BLK 16
#define BLKS_PER_B (S / ROWS_PER_BLK)   // 256
#define NBLK (B * BLKS_PER_B)           // 2048

// online-LSE merge: x = running max, y = running scaled sum
__device__ __forceinline__ float2 lse_merge(float2 A, float2 Bv)
{
    float m = fmaxf(A.x, Bv.x);
    float s = 0.f;
    if (A.y > 0.f)  s += A.y * expf(A.x - m);
    if (Bv.y > 0.f) s += Bv.y * expf(Bv.x - m);
    return make_float2(m, s);
}

// ---------------------------------------------------------------------------
// Kernel 1: thread-per-h-chunk streaming dots. 2048 blocks x 16 rows.
// Thread t owns h-slice [4t, 4t+4): weights = 4 float4 = 16 VGPRs, resident
// by construction (fixes the VGPR=60 weight-reload pathology seen in R6).
// Per row: 1 float4 load + 16 FMAs into acc[r]; 16 independent load streams.
// Reduction: packed butterfly -> 1KB LDS -> wave 0 finalizes 16 rows,
// one coalesced 256B score store + LSE/segment partials.
// ---------------------------------------------------------------------------
__global__ __launch_bounds__(256, 3) void dots_kernel(
    const float4* __restrict__ seq4,
    const float4* __restrict__ Wqa4,     // (H*2/4)
    const float4* __restrict__ Wsp4,     // (H/4)
    const float4* __restrict__ Wrank4,   // (H/4)
    const int*    __restrict__ tt,
    const int*    __restrict__ sent_starts,
    float4* __restrict__ sc4,            // (B*S) {d0,d1,d_sp,d_rank}
    float4* __restrict__ lse_part,       // (NBLK) {m0,s0,m1,s1}
    float4* __restrict__ segpart,        // (NBLK) {jlo(int),sumA,sumB,0}
    float*  __restrict__ out)
{
    const int blk   = blockIdx.x;
    const int b     = blk >> 8;
    const int rbase = (blk & 255) * ROWS_PER_BLK;
    const int t     = threadIdx.x;
    const int w     = t >> 6, lane = t & 63;

    if (blk == 0 && t == 0) { out[0] = 0.f; out[1] = 0.f; out[2] = 0.f; }

    __shared__ float part[ROWS_PER_BLK][16];
    __shared__ int   ssh[NSEG + 1];
    __shared__ int   rowseg[ROWS_PER_BLK];
    __shared__ int   ttsh[ROWS_PER_BLK];
    __shared__ int   jlo_sh;

    // ---- per-thread weights: 4 float4 (16 VGPRs) ----------------------------
    const float4 qA = Wqa4[2 * t];       // {W[4t][0],W[4t][1],W[4t+1][0],W[4t+1][1]}
    const float4 qB = Wqa4[2 * t + 1];   // h = 4t+2, 4t+3
    const float4 sp = Wsp4[t];
    const float4 rk = Wrank4[t];

    // ---- per-block tables ----------------------------------------------------
    if (t < NSEG + 1) ssh[t] = sent_starts[b * (NSEG + 1) + t];
    __syncthreads();
    if (t < ROWS_PER_BLK) {
        ttsh[t] = tt[b * S + rbase + t];
        const int r = rbase + t;
        int j = -1;
        for (int k = 0; k < NSEG; ++k) {
            int en = ssh[k + 1];
            if (en == -1) break;
            if (r >= ssh[k] && r < en) { j = k; break; }
        }
        rowseg[t] = j;
    }
    __syncthreads();
    if (t == 0) {
        int jl = -1;
        for (int i = 0; i < ROWS_PER_BLK; ++i)
            if (rowseg[i] >= 0) { jl = rowseg[i]; break; }
        jlo_sh = jl;
    }
    __syncthreads();
    const int jlo = jlo_sh;

    // ---- streaming: 16 rows, thread reads its fixed chunk of each row -------
    const float4* base = seq4 + (size_t)(b * S + rbase) * (H / 4) + t;

    float4 acc[ROWS_PER_BLK];
    float4 v[8];
#pragma unroll
    for (int r = 0; r < 8; ++r) v[r] = base[(size_t)r * (H / 4)];
#pragma unroll
    for (int r = 0; r < 8; ++r) {
        float4 x = v[r], a;
        a.x = x.x * qA.x + x.y * qA.z + x.z * qB.x + x.w * qB.z;
        a.y = x.x * qA.y + x.y * qA.w + x.z * qB.y + x.w * qB.w;
        a.z = x.x * sp.x + x.y * sp.y + x.z * sp.z + x.w * sp.w;
        a.w = x.x * rk.x + x.y * rk.y + x.z * rk.z + x.w * rk.w;
        acc[r] = a;
    }
#pragma unroll
    for (int r = 0; r < 8; ++r) v[r] = base[(size_t)(r + 8) * (H / 4)];
#pragma unroll
    for (int r = 0; r < 8; ++r) {
        float4 x = v[r], a;
        a.x = x.x * qA.x + x.y * qA.z + x.z * qB.x + x.w * qB.z;
        a.y = x.x * qA.y + x.y * qA.w + x.z * qB.y + x.w * qB.w;
        a.z = x.x * sp.x + x.y * sp.y + x.z * sp.z + x.w * sp.w;
        a.w = x.x * rk.x + x.y * rk.y + x.z * rk.z + x.w * rk.w;
        acc[r + 8] = a;
    }

    // ---- per-row packed butterfly (7 shuffles); wave partial -> LDS ---------
#pragma unroll
    for (int r = 0; r < ROWS_PER_BLK; ++r) {
        float4 a = acc[r];
        float u01 = (lane & 1) ? a.x : a.y;
        float x01 = ((lane & 1) ? a.y : a.x) + __shfl_xor(u01, 1);
        float u23 = (lane & 1) ? a.z : a.w;
        float x23 = ((lane & 1) ? a.w : a.z) + __shfl_xor(u23, 1);
        float uu  = (lane & 2) ? x01 : x23;
        float x   = ((lane & 2) ? x23 : x01) + __shfl_xor(uu, 2);
        x += __shfl_xor(x, 4);  x += __shfl_xor(x, 8);
        x += __shfl_xor(x, 16); x += __shfl_xor(x, 32);
        if (lane < 4) part[r][w * 4 + lane] = x;   // class k at lane k
    }
    __syncthreads();

    // ---- wave 0 finalizes: lane = r*4 + k -----------------------------------
    if (w == 0) {
        const int r = lane >> 2, k = lane & 3;
        float x = part[r][k] + part[r][4 + k] + part[r][8 + k] + part[r][12 + k];
        ((float*)(sc4 + (size_t)b * S + rbase))[lane] = x;   // 256B coalesced

        const bool inc = (ttsh[r] == 1);
        float mx = inc ? x : -INFINITY;
#pragma unroll
        for (int off = 4; off < 64; off <<= 1) mx = fmaxf(mx, __shfl_xor(mx, off));
        float ex = inc ? expf(x - mx) : 0.f;
        const int j = rowseg[r];
        float sA = (j >= 0 && j == jlo) ? x : 0.f;
        float sB = (j >= 0 && j != jlo) ? x : 0.f;
#pragma unroll
        for (int off = 4; off < 64; off <<= 1) {
            ex += __shfl_xor(ex, off);
            sA += __shfl_xor(sA, off);
            sB += __shfl_xor(sB, off);
        }
        // class k=0 lanes hold start-LSE, k=1 end-LSE, k=2 segment sums
        float m1  = __shfl(mx, 1), s1 = __shfl(ex, 1);
        float sa2 = __shfl(sA, 2), sb2 = __shfl(sB, 2);
        if (lane == 0) {
            lse_part[blk] = make_float4(mx, ex, m1, s1);
            segpart[blk]  = make_float4(__int_as_float(jlo), sa2, sb2, 0.f);
        }
    }
}

// ---------------------------------------------------------------------------
// block reduce (sum) for ListMLE
// ---------------------------------------------------------------------------
__device__ __forceinline__ float blk_reduce1(float v, float* wred1, int t)
{
    const int lane = t & 63, w = t >> 6;
#pragma unroll
    for (int off = 32; off > 0; off >>= 1) v += __shfl_xor(v, off);
    if (lane == 0) wred1[w] = v;
    __syncthreads();
    float r = wred1[0] + wred1[1] + wred1[2] + wred1[3];
    __syncthreads();
    return r;
}

__device__ float listmle_block(const float* fs, const float* fl, float* se,
                               int n, float* wred1, int t)
{
    if (t < n) se[t] = (fl[t] != -1.0f) ? expf(fs[t]) : 0.0f;
    __syncthreads();
    float lp = 0.0f;
    if (t < n && fl[t] >= 0.5f) {
        float fj = fl[t];
        float rest = 0.0f;
        for (int k = 0; k < n; ++k)
            if (fl[k] < fj) rest += se[k];
        lp = fs[t] - logf(se[t] + rest);
    }
    float tot = blk_reduce1(lp, wred1, t);
    return -tot;
}

// ---------------------------------------------------------------------------
// Kernel 2: one block per batch. Merge 256 LSE partials, fold 256 segment
// partials (LDS atomics), 2x ListMLE, span loss; atomicAdd into out.
// ---------------------------------------------------------------------------
__global__ __launch_bounds__(256) void batch_kernel(
    const float4* __restrict__ sc4,
    const float4* __restrict__ lse_part,
    const float4* __restrict__ segpart,
    const int*    __restrict__ tt,
    const int*    __restrict__ sent_starts,
    const int*    __restrict__ para_starts,
    const float*  __restrict__ para_labels,
    const float*  __restrict__ sp_labels,
    const int*    __restrict__ starts,
    const int*    __restrict__ ends,
    float* __restrict__ out)
{
    const int b = blockIdx.x;
    const int t = threadIdx.x;
    const int lane = t & 63, w = t >> 6;

    __shared__ float4 lsew[4];
    __shared__ float  segsum[NSEG + 2];
    __shared__ int    ssh[NSEG + 1];
    __shared__ float  wred1[4];
    __shared__ float  fsb[1 + NSEG], flb[1 + NSEG], seb[1 + NSEG];
    __shared__ float  lse_sh[2];

    const float4* sb  = sc4 + (size_t)b * S;
    const int*    ttb = tt + b * S;

    if (t < NSEG + 2) segsum[t] = 0.f;
    if (t < NSEG + 1) ssh[t] = sent_starts[b * (NSEG + 1) + t];
    __syncthreads();

    // ---- merge 256 LSE partials + fold 256 segment partials -----------------
    {
        float4 P = lse_part[(size_t)b * BLKS_PER_B + t];
        float2 L0 = make_float2(P.x, P.y);
        float2 L1 = make_float2(P.z, P.w);
#pragma unroll
        for (int off = 32; off > 0; off >>= 1) {
            float2 O0 = make_float2(__shfl_xor(L0.x, off), __shfl_xor(L0.y, off));
            float2 O1 = make_float2(__shfl_xor(L1.x, off), __shfl_xor(L1.y, off));
            L0 = lse_merge(L0, O0);
            L1 = lse_merge(L1, O1);
        }
        if (lane == 0) lsew[w] = make_float4(L0.x, L0.y, L1.x, L1.y);

        float4 SP = segpart[(size_t)b * BLKS_PER_B + t];
        int jl = __float_as_int(SP.x);
        if (jl >= 0) {
            atomicAdd(&segsum[jl], SP.y);
            atomicAdd(&segsum[jl + 1], SP.z);
        }
    }
    __syncthreads();
    if (t == 0) {
        float2 M0 = make_float2(lsew[0].x, lsew[0].y);
        float2 M1 = make_float2(lsew[0].z, lsew[0].w);
#pragma unroll
        for (int i = 1; i < 4; ++i) {
            M0 = lse_merge(M0, make_float2(lsew[i].x, lsew[i].y));
            M1 = lse_merge(M1, make_float2(lsew[i].z, lsew[i].w));
        }
        lse_sh[0] = M0.x + logf(M0.y);
        lse_sh[1] = M1.x + logf(M1.y);
    }

    // ---- sp ListMLE ---------------------------------------------------------
    if (t == 0) { fsb[0] = sb[0].z; flb[0] = 0.5f; }       // sent_thres
    if (t < NSEG) {
        int st = ssh[t];
        int en = ssh[t + 1];
        float score;
        if (en != -1) {
            int stc = min(max(st, 0), S);
            int enc = max(min(max(en, 0), S), stc + 1);
            score = segsum[t] / (float)(enc - stc);
        } else {
            score = sb[S - 1].z;                           // d_sp at last row
        }
        fsb[1 + t] = score;
        flb[1 + t] = sp_labels[b * NSEG + t];
    }
    __syncthreads();
    float sp_loss_b = listmle_block(fsb, flb, seb, 1 + NSEG, wred1, t);

    // ---- rank ListMLE -------------------------------------------------------
    if (t == 0) { fsb[0] = sb[0].w; flb[0] = 0.5f; }       // rank_thres
    if (t < NPARA) {
        int ps = para_starts[b * NPARA + t];
        fsb[1 + t] = sb[ps].w;
        flb[1 + t] = para_labels[b * NPARA + t];
    }
    __syncthreads();
    float rank_loss_b = listmle_block(fsb, flb, seb, 1 + NPARA, wred1, t);

    // ---- span loss (parallel over answers) ----------------------------------
    float e_a = 0.f;
    if (t < NA) {
        const float lse0 = lse_sh[0], lse1 = lse_sh[1];
        int tsv = starts[b * NA + t];
        int tev = ends[b * NA + t];
        float lt = 0.f;
        if (tsv != -1) {
            int sf = min(max(tsv, 0), S - 1);
            float sl = (ttb[sf] == 1) ? sb[sf].x : -INFINITY;
            lt += -(sl - lse0);
        }
        if (tev != -1) {
            int sf = min(max(tev, 0), S - 1);
            float el = (ttb[sf] == 1) ? sb[sf].y : -INFINITY;
            lt += -(el - lse1);
        }
        float lp = -lt;
        e_a = (lp == 0.0f) ? 0.f : expf(lp);
    }
#pragma unroll
    for (int off = 4; off > 0; off >>= 1) e_a += __shfl_xor(e_a, off, 8);
    if (t == 0) {
        float logm = (e_a > 0.f) ? logf(e_a) : 0.f;
        atomicAdd(out + 0, rank_loss_b + sp_loss_b - logm);
        atomicAdd(out + 1, rank_loss_b);
        atomicAdd(out + 2, sp_loss_b);
    }
}

extern "C" void kernel_launch(void* const* d_in, const int* in_sizes, int n_in,
                              void* d_out, int out_size, void* d_ws, size_t ws_size,
                              hipStream_t stream)
{
    const float* seq         = (const float*)d_in[0];
    const int*   tt          = (const int*)  d_in[1];
    const int*   sent_starts = (const int*)  d_in[2];
    const int*   para_starts = (const int*)  d_in[3];
    const float* para_labels = (const float*)d_in[4];
    const float* sp_labels   = (const float*)d_in[5];
    const int*   starts      = (const int*)  d_in[6];
    const int*   ends        = (const int*)  d_in[7];
    const float* Wqa         = (const float*)d_in[8];
    const float* Wrank       = (const float*)d_in[10];
    const float* Wsp         = (const float*)d_in[12];

    float*  out      = (float*)d_out;
    float4* sc4      = (float4*)d_ws;            // B*S float4 = 512 KB
    float4* lse_part = sc4 + (size_t)BS;         // NBLK
    float4* segpart  = lse_part + NBLK;          // NBLK

    dots_kernel<<<NBLK, 256, 0, stream>>>((const float4*)seq,
                                          (const float4*)Wqa,
                                          (const float4*)Wsp,
                                          (const float4*)Wrank,
                                          tt, sent_starts,
                                          sc4, lse_part, segpart, out);
    batch_kernel<<<B, 256, 0, stream>>>(sc4, lse_part, segpart, tt, sent_starts,
                                        para_starts, para_labels, sp_labels,
                                        starts, ends, out);
}

// Round 10
// 38.555 us; speedup vs baseline: 1.2006x; 1.1314x over previous
//
#include <hip/hip_runtime.h>
#include <math.h>

#define B 8
#define S 4096
#define H 1024
#define NSEG 64
#define NPARA 32
#define NA 8
#define BS (B * S)
#define ROWS_PER_BLK 16
#define BLKS_PER_B (S / ROWS_PER_BLK)      // 256
#define NBLK (B * BLKS_PER_B)              // 2048

// online-LSE merge: x = running max (m), y = running scaled sum (s)
__device__ __forceinline__ float2 lse_merge(float2 A, float2 Bv)
{
    float m = fmaxf(A.x, Bv.x);
    float s = 0.f;
    if (A.y > 0.f)  s += A.y * expf(A.x - m);
    if (Bv.y > 0.f) s += Bv.y * expf(Bv.x - m);
    return make_float2(m, s);
}

// ---------------------------------------------------------------------------
// Kernel 1 (champion R3, verbatim): per-row 4-way dots + fused online masked
// logsumexp partials. Block k handles 16 contiguous rows of batch k/256.
// One wave per 4 rows. Planar scores (4, B*S); per-block LSE partial float4.
// ---------------------------------------------------------------------------
__global__ __launch_bounds__(256) void dots_kernel(
    const float* __restrict__ seq,
    const float* __restrict__ Wqa,
    const float* __restrict__ Wsp,
    const float* __restrict__ Wrank,
    const int*   __restrict__ tt,
    float* __restrict__ scores,
    float4* __restrict__ lse_part,
    float* __restrict__ out)
{
    if (blockIdx.x == 0 && threadIdx.x == 0) {
        out[0] = 0.f; out[1] = 0.f; out[2] = 0.f;
    }
    const int blk   = blockIdx.x;
    const int b     = blk >> 8;                 // batch
    const int rbase = (blk & 255) * ROWS_PER_BLK;
    const int w     = threadIdx.x >> 6;
    const int lane  = threadIdx.x & 63;

    __shared__ float  blkres[4][ROWS_PER_BLK];
    __shared__ float4 lsep[4];

    // preload weights (lane handles float4 chunks lane + 64*c)
    float wq0[4][4], wq1[4][4];
    float4 wspv[4], wrkv[4];
#pragma unroll
    for (int c = 0; c < 4; ++c) {
        int h0 = (lane + 64 * c) * 4;
#pragma unroll
        for (int j = 0; j < 4; ++j) {
            wq0[c][j] = Wqa[(h0 + j) * 2 + 0];
            wq1[c][j] = Wqa[(h0 + j) * 2 + 1];
        }
        wspv[c] = *(const float4*)(Wsp + h0);
        wrkv[c] = *(const float4*)(Wrank + h0);
    }

    const int* ttb = tt + b * S;
    float m0 = -INFINITY, s0 = 0.f, m1 = -INFINITY, s1 = 0.f;

    for (int i = 0; i < 4; ++i) {
        const int srow = rbase + w * 4 + i;
        const float4* row = (const float4*)(seq + ((size_t)b * S + srow) * H);
        float a0 = 0.f, a1 = 0.f, a2 = 0.f, a3 = 0.f;
#pragma unroll
        for (int c = 0; c < 4; ++c) {
            float4 v = row[lane + 64 * c];
            a0 += v.x * wq0[c][0] + v.y * wq0[c][1] + v.z * wq0[c][2] + v.w * wq0[c][3];
            a1 += v.x * wq1[c][0] + v.y * wq1[c][1] + v.z * wq1[c][2] + v.w * wq1[c][3];
            a2 += v.x * wspv[c].x + v.y * wspv[c].y + v.z * wspv[c].z + v.w * wspv[c].w;
            a3 += v.x * wrkv[c].x + v.y * wrkv[c].y + v.z * wrkv[c].z + v.w * wrkv[c].w;
        }
#pragma unroll
        for (int off = 32; off > 0; off >>= 1) {
            a0 += __shfl_xor(a0, off);
            a1 += __shfl_xor(a1, off);
            a2 += __shfl_xor(a2, off);
            a3 += __shfl_xor(a3, off);
        }
        // fused online masked LSE (lane-uniform, biases cancel: shift-invariant)
        if (ttb[srow] == 1) {
            float mn = fmaxf(m0, a0);
            s0 = s0 * expf(m0 - mn) + expf(a0 - mn); m0 = mn;
            mn = fmaxf(m1, a1);
            s1 = s1 * expf(m1 - mn) + expf(a1 - mn); m1 = mn;
        }
        if (lane == 0) {
            const int idx = w * 4 + i;
            blkres[0][idx] = a0; blkres[1][idx] = a1;
            blkres[2][idx] = a2; blkres[3][idx] = a3;
        }
    }
    if (lane == 0) lsep[w] = make_float4(m0, s0, m1, s1);
    __syncthreads();

    const int t = threadIdx.x;
    if (t < 64) {   // coalesced score writes: 4 planes x 16 floats
        const int p = t >> 4, idx = t & 15;
        scores[p * BS + b * S + rbase + idx] = blkres[p][idx];
    }
    if (t == 0) {   // merge the 4 wave partials
        float2 L0 = make_float2(lsep[0].x, lsep[0].y);
        float2 L1 = make_float2(lsep[0].z, lsep[0].w);
#pragma unroll
        for (int i = 1; i < 4; ++i) {
            L0 = lse_merge(L0, make_float2(lsep[i].x, lsep[i].y));
            L1 = lse_merge(L1, make_float2(lsep[i].z, lsep[i].w));
        }
        lse_part[blk] = make_float4(L0.x, L0.y, L1.x, L1.y);
    }
}

// ---------------------------------------------------------------------------
// block reduce (sum) for ListMLE
// ---------------------------------------------------------------------------
__device__ __forceinline__ float blk_reduce1(float v, float* wred1, int t)
{
    const int lane = t & 63, w = t >> 6;
#pragma unroll
    for (int off = 32; off > 0; off >>= 1) v += __shfl_xor(v, off);
    if (lane == 0) wred1[w] = v;
    __syncthreads();
    float r = wred1[0] + wred1[1] + wred1[2] + wred1[3];
    __syncthreads();
    return r;
}

__device__ float listmle_block(const float* fs, const float* fl, float* se,
                               int n, float* wred1, int t)
{
    if (t < n) se[t] = (fl[t] != -1.0f) ? expf(fs[t]) : 0.0f;
    __syncthreads();
    float lp = 0.0f;
    if (t < n && fl[t] >= 0.5f) {
        float fj = fl[t];
        float rest = 0.0f;
        for (int k = 0; k < n; ++k)
            if (fl[k] < fj) rest += se[k];
        lp = fs[t] - logf(se[t] + rest);
    }
    float tot = blk_reduce1(lp, wred1, t);
    return -tot;
}

// ---------------------------------------------------------------------------
// Kernel 2: one block per batch. Merge LSE partials (4KB), DIRECT per-segment
// sums of p2 (4 threads per segment, contiguous reads — replaces the S-scan),
// 2x ListMLE, parallel span loss; atomicAdd into out.
// ---------------------------------------------------------------------------
__global__ __launch_bounds__(256) void batch_kernel(
    const float*  __restrict__ scores,
    const float4* __restrict__ lse_part,
    const int*    __restrict__ tt,
    const int*    __restrict__ sent_starts,
    const int*    __restrict__ para_starts,
    const float*  __restrict__ para_labels,
    const float*  __restrict__ sp_labels,
    const int*    __restrict__ starts,
    const int*    __restrict__ ends,
    float* __restrict__ out)
{
    const int b = blockIdx.x;
    const int t = threadIdx.x;
    const int lane = t & 63, w = t >> 6;

    __shared__ float4 lsew[4];
    __shared__ float  wred1[4];
    __shared__ float  fsb[1 + NSEG], flb[1 + NSEG], seb[1 + NSEG];
    __shared__ float  lse_sh[2];
    __shared__ int    ssh[NSEG + 1];

    const float* p0 = scores + 0 * BS + b * S;
    const float* p1 = scores + 1 * BS + b * S;
    const float* p2 = scores + 2 * BS + b * S;
    const float* p3 = scores + 3 * BS + b * S;
    const int*   ttb = tt + b * S;

    if (t < NSEG + 1) ssh[t] = sent_starts[b * (NSEG + 1) + t];

    // ---- merge 256 LSE partials ---------------------------------------------
    {
        float4 P = lse_part[b * BLKS_PER_B + t];
        float2 L0 = make_float2(P.x, P.y);
        float2 L1 = make_float2(P.z, P.w);
#pragma unroll
        for (int off = 32; off > 0; off >>= 1) {
            float2 O0 = make_float2(__shfl_xor(L0.x, off), __shfl_xor(L0.y, off));
            float2 O1 = make_float2(__shfl_xor(L1.x, off), __shfl_xor(L1.y, off));
            L0 = lse_merge(L0, O0);
            L1 = lse_merge(L1, O1);
        }
        if (lane == 0) lsew[w] = make_float4(L0.x, L0.y, L1.x, L1.y);
        __syncthreads();
        if (t == 0) {
            float2 M0 = make_float2(lsew[0].x, lsew[0].y);
            float2 M1 = make_float2(lsew[0].z, lsew[0].w);
#pragma unroll
            for (int i = 1; i < 4; ++i) {
                M0 = lse_merge(M0, make_float2(lsew[i].x, lsew[i].y));
                M1 = lse_merge(M1, make_float2(lsew[i].z, lsew[i].w));
            }
            lse_sh[0] = M0.x + logf(M0.y);
            lse_sh[1] = M1.x + logf(M1.y);
        }
    }

    // ---- direct per-segment sums of p2 (replaces the prefix scan) -----------
    {
        const int j  = t >> 2;        // segment 0..63
        const int l4 = t & 3;
        int st = ssh[j];
        int en = ssh[j + 1];
        if (en != -1) {
            int stc = min(max(st, 0), S);
            int enc = max(min(max(en, 0), S), stc + 1);
            float x = 0.f;
            for (int s = stc + l4; s < enc; s += 4) x += p2[s];
            x += __shfl_xor(x, 1);
            x += __shfl_xor(x, 2);
            if (l4 == 0) {
                fsb[1 + j] = x / (float)(enc - stc);
                flb[1 + j] = sp_labels[b * NSEG + j];
            }
        } else {
            if (l4 == 0) {
                fsb[1 + j] = p2[S - 1];       // d_sp at last row
                flb[1 + j] = sp_labels[b * NSEG + j];
            }
        }
        if (t == 0) { fsb[0] = p2[0]; flb[0] = 0.5f; }   // sent_thres
    }
    __syncthreads();
    float sp_loss_b = listmle_block(fsb, flb, seb, 1 + NSEG, wred1, t);

    // ---- rank ListMLE -------------------------------------------------------
    if (t == 0) { fsb[0] = p3[0]; flb[0] = 0.5f; }
    if (t < NPARA) {
        int ps = para_starts[b * NPARA + t];
        fsb[1 + t] = p3[ps];
        flb[1 + t] = para_labels[b * NPARA + t];
    }
    __syncthreads();
    float rank_loss_b = listmle_block(fsb, flb, seb, 1 + NPARA, wred1, t);

    // ---- span loss (parallel over answers) ----------------------------------
    float e_a = 0.f;
    if (t < NA) {
        const float lse0 = lse_sh[0], lse1 = lse_sh[1];
        int tsv = starts[b * NA + t];
        int tev = ends[b * NA + t];
        float lt = 0.f;
        if (tsv != -1) {
            int sf = min(max(tsv, 0), S - 1);
            float sl = (ttb[sf] == 1) ? p0[sf] : -INFINITY;
            lt += -(sl - lse0);
        }
        if (tev != -1) {
            int sf = min(max(tev, 0), S - 1);
            float el = (ttb[sf] == 1) ? p1[sf] : -INFINITY;
            lt += -(el - lse1);
        }
        float lp = -lt;
        e_a = (lp == 0.0f) ? 0.f : expf(lp);
    }
#pragma unroll
    for (int off = 4; off > 0; off >>= 1) e_a += __shfl_xor(e_a, off, 8);
    if (t == 0) {
        float logm = (e_a > 0.f) ? logf(e_a) : 0.f;
        atomicAdd(out + 0, rank_loss_b + sp_loss_b - logm);
        atomicAdd(out + 1, rank_loss_b);
        atomicAdd(out + 2, sp_loss_b);
    }
}

extern "C" void kernel_launch(void* const* d_in, const int* in_sizes, int n_in,
                              void* d_out, int out_size, void* d_ws, size_t ws_size,
                              hipStream_t stream)
{
    const float* seq         = (const float*)d_in[0];
    const int*   tt          = (const int*)  d_in[1];
    const int*   sent_starts = (const int*)  d_in[2];
    const int*   para_starts = (const int*)  d_in[3];
    const float* para_labels = (const float*)d_in[4];
    const float* sp_labels   = (const float*)d_in[5];
    const int*   starts      = (const int*)  d_in[6];
    const int*   ends        = (const int*)  d_in[7];
    const float* Wqa         = (const float*)d_in[8];
    const float* Wrank       = (const float*)d_in[10];
    const float* Wsp         = (const float*)d_in[12];

    float*  out      = (float*)d_out;
    float*  scores   = (float*)d_ws;                       // planar (4, B*S)
    float4* lse_part = (float4*)(scores + 4 * (size_t)BS); // NBLK float4

    dots_kernel<<<NBLK, 256, 0, stream>>>(seq, Wqa, Wsp, Wrank, tt,
                                          scores, lse_part, out);
    batch_kernel<<<B, 256, 0, stream>>>(scores, lse_part, tt, sent_starts,
                                        para_starts, para_labels, sp_labels,
                                        starts, ends, out);
}